// Round 6
// baseline (79.072 us; speedup 1.0000x reference)
//
#include <hip/hip_runtime.h>

// Problem constants (fixed by setup_inputs): lfi [B,A,H,W,C], f_maps [B,H,W,F]
#define BB 4
#define AA 9
#define HH 256
#define WW 256
#define CC 9
#define FF 64

// ---------------------------------------------------------------------------
// Kernel 1 (== round-1 k_hv, proven): hv[b,w,f] = mean_h f_maps[b,h,w,f]
// Block per (b,w): 256 threads = 4 h-lanes (hl) x 64 f. Each wave reads a
// contiguous 256B span (f=0..63) per h step; LDS-reduce across the 4 hl.
// ---------------------------------------------------------------------------
__global__ __launch_bounds__(256) void k_hv(const float* __restrict__ fm,
                                            float* __restrict__ hv) {
    const int blk = blockIdx.x;       // b*WW + w
    const int b = blk >> 8;           // WW == 256
    const int w = blk & 255;
    const int f = threadIdx.x & 63;
    const int hl = threadIdx.x >> 6;  // 0..3

    const float* base = fm + (((size_t)b * HH) * WW + w) * FF + f;
    float s = 0.f;
#pragma unroll 8
    for (int h = hl; h < HH; h += 4) {
        s += base[(size_t)h * WW * FF];
    }
    __shared__ float sm[256];
    sm[threadIdx.x] = s;
    __syncthreads();
    if (hl == 0) {
        float t = sm[f] + sm[64 + f] + sm[128 + f] + sm[192 + f];
        hv[(size_t)blk * FF + f] = t * (1.0f / HH);
    }
}

// ---------------------------------------------------------------------------
// Kernel 2 (== round-1 k_m + 4 rider blocks replacing the k_inv dispatch):
//  blocks [0,1024):   m[b,h,w] = mean_{a,c} lfi[b,a,h,w,c] (round-1 body)
//  blocks [1024,1028): block 1024+b, threads t<64: inv[b,f=t] = 1/max_w hv.
//    Row scan: per w the wave reads hv[b][w][0..63] = 256B contiguous,
//    L2/L3-resident (hv was just written by k_hv) — hides under the m blocks.
// ---------------------------------------------------------------------------
__global__ __launch_bounds__(256) void k_m(const float* __restrict__ lfi,
                                           const float* __restrict__ hv,
                                           float* __restrict__ m,
                                           float* __restrict__ inv) {
    if (blockIdx.x < 1024) {
        const int gid = blockIdx.x * 256 + threadIdx.x;  // b*HH*WW + h*WW + w
        const int b = gid >> 16;                         // HH*WW == 65536
        const int hw = gid & 65535;

        const size_t astride = (size_t)HH * WW * CC;  // 589824
        const float* base = lfi + (size_t)b * AA * astride + (size_t)hw * CC;

        float s = 0.f;
#pragma unroll
        for (int a = 0; a < AA; ++a) {
            const float* p = base + (size_t)a * astride;
#pragma unroll
            for (int c = 0; c < CC; ++c) s += p[c];
        }
        m[gid] = s * (1.0f / (AA * CC));
    } else {
        const int b = blockIdx.x - 1024;  // 0..3
        const int t = threadIdx.x;
        if (t < FF) {
            float mx = -1e30f;
#pragma unroll 8
            for (int w = 0; w < WW; ++w)
                mx = fmaxf(mx, hv[((size_t)b * WW + w) * FF + t]);
            inv[b * FF + t] = 1.0f / mx;
        }
    }
}

// ---------------------------------------------------------------------------
// Kernel 3 (== round-1 k_out, proven): out[b,h,w,f] = m * hv[b,h,f] * inv[b,f]
// One thread per float4 along f; contiguous 16B/lane stores.
// ---------------------------------------------------------------------------
__global__ __launch_bounds__(256) void k_out(const float* __restrict__ m,
                                             const float* __restrict__ hv,
                                             const float* __restrict__ inv,
                                             float4* __restrict__ out) {
    const int idx = blockIdx.x * 256 + threadIdx.x;  // over B*H*W*F/4
    const int f4 = idx & 15;                         // FF/4 == 16
    const int rest = idx >> 4;                       // b*HH*WW + h*WW + w
    const int h = (rest >> 8) & 255;
    const int b = rest >> 16;

    const float mv = m[rest];
    const float4 hv4 = ((const float4*)hv)[((size_t)(b * HH + h)) * (FF / 4) + f4];
    const float4 iv4 = ((const float4*)inv)[b * (FF / 4) + f4];

    float4 o;
    o.x = mv * hv4.x * iv4.x;
    o.y = mv * hv4.y * iv4.y;
    o.z = mv * hv4.z * iv4.z;
    o.w = mv * hv4.w * iv4.w;
    out[idx] = o;
}

extern "C" void kernel_launch(void* const* d_in, const int* in_sizes, int n_in,
                              void* d_out, int out_size, void* d_ws, size_t ws_size,
                              hipStream_t stream) {
    const float* lfi = (const float*)d_in[0];  // [B,A,H,W,C] f32
    const float* fm  = (const float*)d_in[1];  // [B,H,W,F]   f32
    float* out = (float*)d_out;                // [B,H,W,F]   f32

    // Workspace layout (as round 1): hv 256KB | inv 1KB | m 1MB
    char* ws = (char*)d_ws;
    float* hv  = (float*)ws;
    float* inv = (float*)(ws + (size_t)BB * WW * FF * 4);
    float* m   = (float*)(ws + (size_t)BB * WW * FF * 4 + 1024);

    // 1) column means of f_maps
    k_hv<<<BB * WW, 256, 0, stream>>>(fm, hv);
    // 2) angular mean of lfi + rider blocks computing inv (replaces k_inv)
    k_m<<<1024 + BB, 256, 0, stream>>>(lfi, hv, m, inv);
    // 3) broadcast-multiply into out
    k_out<<<(BB * HH * WW * FF / 4) / 256, 256, 0, stream>>>(m, hv, inv,
                                                             (float4*)out);
}

// Round 7
// 50.061 us; speedup vs baseline: 1.5795x; 1.5795x over previous
//
#include <hip/hip_runtime.h>

// Problem constants (fixed by setup_inputs): lfi [B,A,H,W,C], f_maps [B,H,W,F]
#define BB 4
#define AA 9
#define HH 256
#define WW 256
#define CC 9
#define FF 64

// ---------------------------------------------------------------------------
// Kernel 1 (round-1 verbatim, proven ~11us): hv[b,w,f] = mean_h f_maps[b,h,w,f]
// Block per (b,w): 256 threads = 4 h-lanes x 64 f; 256B/wave contiguous loads.
// ---------------------------------------------------------------------------
__global__ __launch_bounds__(256) void k_hv(const float* __restrict__ fm,
                                            float* __restrict__ hv) {
    const int blk = blockIdx.x;       // b*WW + w
    const int b = blk >> 8;           // WW == 256
    const int w = blk & 255;
    const int f = threadIdx.x & 63;
    const int hl = threadIdx.x >> 6;  // 0..3

    const float* base = fm + (((size_t)b * HH) * WW + w) * FF + f;
    float s = 0.f;
#pragma unroll 8
    for (int h = hl; h < HH; h += 4) {
        s += base[(size_t)h * WW * FF];
    }
    __shared__ float sm[256];
    sm[threadIdx.x] = s;
    __syncthreads();
    if (hl == 0) {
        float t = sm[f] + sm[64 + f] + sm[128 + f] + sm[192 + f];
        hv[(size_t)blk * FF + f] = t * (1.0f / HH);
    }
}

// ---------------------------------------------------------------------------
// Kernel 2 (round-1 verbatim, proven ~3us): inv[b,f] = 1 / max_w hv[b,w,f]
// Block per (b,f): 64 lanes x 4 w each + shuffle-max. L2-resident reads.
// ---------------------------------------------------------------------------
__global__ __launch_bounds__(64) void k_inv(const float* __restrict__ hv,
                                            float* __restrict__ inv) {
    const int b = blockIdx.x >> 6;
    const int f = blockIdx.x & 63;
    const int t = threadIdx.x;
    float mx = -1e30f;
#pragma unroll
    for (int j = 0; j < 4; ++j) {
        mx = fmaxf(mx, hv[((size_t)b * WW + (t + 64 * j)) * FF + f]);
    }
#pragma unroll
    for (int off = 32; off; off >>= 1)
        mx = fmaxf(mx, __shfl_xor(mx, off));
    if (t == 0) inv[blockIdx.x] = 1.0f / mx;
}

// ---------------------------------------------------------------------------
// Kernel 3: m partials via float4 loads (1 L1 line-request per line instead
// of 9 with stride-36B scalar loads — round-6 counters show scalar k_m is
// L1-transaction-bound at ~18us vs 13.5us HBM floor).
// Thread owns 4 consecutive hw (= 9 float4 per a, 1KB/wave contiguous).
// 3-way a-split (role 0: a=0..2, 1: a=3..5, 2: a=6..8) -> 768 blocks,
// 12 waves/CU. k_out sums the three partials. STANDALONE kernel (no role
// fusion -> no register-allocation coupling).
// ---------------------------------------------------------------------------
__global__ __launch_bounds__(256) void k_m3(const float* __restrict__ lfi,
                                            float* __restrict__ mpart) {
    const int t = threadIdx.x;
    const int role = blockIdx.x >> 8;              // 0,1,2
    const int hw4 = (blockIdx.x & 255) * 256 + t;  // 0..65535
    const int b = hw4 >> 14;                       // 16384 hw4 per batch
    const int hwl = (hw4 & 16383) * 4;             // local hw start
    const size_t astride4 = (size_t)HH * WW * CC / 4;  // 147456 float4

    const float4* base =
        (const float4*)(lfi + (size_t)b * AA * (astride4 * 4)) +
        (size_t)hwl * CC / 4;
    float4 acc = make_float4(0.f, 0.f, 0.f, 0.f);
#pragma unroll
    for (int a = role * 3; a < role * 3 + 3; ++a) {
        const float4* p = base + (size_t)a * astride4;
        float4 v0 = p[0], v1 = p[1], v2 = p[2], v3 = p[3], v4 = p[4];
        float4 v5 = p[5], v6 = p[6], v7 = p[7], v8 = p[8];
        // 36 consecutive floats -> 4 outputs of 9 floats each (static map)
        acc.x += v0.x + v0.y + v0.z + v0.w + v1.x + v1.y + v1.z + v1.w + v2.x;
        acc.y += v2.y + v2.z + v2.w + v3.x + v3.y + v3.z + v3.w + v4.x + v4.y;
        acc.z += v4.z + v4.w + v5.x + v5.y + v5.z + v5.w + v6.x + v6.y + v6.z;
        acc.w += v6.w + v7.x + v7.y + v7.z + v7.w + v8.x + v8.y + v8.z + v8.w;
    }
    ((float4*)mpart)[(size_t)role * 65536 + hw4] = acc;
}

// ---------------------------------------------------------------------------
// Kernel 4: out[b,h,w,f] = m[b,h,w] * hv[b,h,f] * inv[b,f]
// m = sum of 3 a-range partials * 1/81. 16B/lane contiguous stores.
// ---------------------------------------------------------------------------
__global__ __launch_bounds__(256) void k_out(const float* __restrict__ mpart,
                                             const float* __restrict__ hv,
                                             const float* __restrict__ inv,
                                             float4* __restrict__ out) {
    const int idx = blockIdx.x * 256 + threadIdx.x;  // over B*H*W*F/4
    const int f4 = idx & 15;                         // FF/4 == 16
    const int rest = idx >> 4;                       // b*HH*WW + h*WW + w
    const int h = (rest >> 8) & 255;
    const int b = rest >> 16;

    const float mv = (mpart[rest] + mpart[262144 + rest] +
                      mpart[524288 + rest]) * (1.0f / (AA * CC));
    const float4 hv4 = ((const float4*)hv)[((size_t)(b * HH + h)) * (FF / 4) + f4];
    const float4 iv4 = ((const float4*)inv)[b * (FF / 4) + f4];

    float4 o;
    o.x = mv * hv4.x * iv4.x;
    o.y = mv * hv4.y * iv4.y;
    o.z = mv * hv4.z * iv4.z;
    o.w = mv * hv4.w * iv4.w;
    out[idx] = o;
}

extern "C" void kernel_launch(void* const* d_in, const int* in_sizes, int n_in,
                              void* d_out, int out_size, void* d_ws, size_t ws_size,
                              hipStream_t stream) {
    const float* lfi = (const float*)d_in[0];  // [B,A,H,W,C] f32
    const float* fm  = (const float*)d_in[1];  // [B,H,W,F]   f32
    float* out = (float*)d_out;                // [B,H,W,F]   f32

    // ws layout: hv 256KB | inv 4KB | mpart 3MB
    char* ws = (char*)d_ws;
    float* hv   = (float*)ws;
    float* inv  = (float*)(ws + (size_t)BB * WW * FF * 4);
    float* mprt = (float*)(ws + (size_t)BB * WW * FF * 4 + 4096);

    // 1) column means of f_maps
    k_hv<<<BB * WW, 256, 0, stream>>>(fm, hv);
    // 2) per-(b,f) reciprocal of max over w (parallel, 256 blocks)
    k_inv<<<BB * FF, 64, 0, stream>>>(hv, inv);
    // 3) angular-mean partials of lfi (float4, 3-way a-split)
    k_m3<<<3 * 256, 256, 0, stream>>>(lfi, mprt);
    // 4) broadcast-multiply into out
    k_out<<<(BB * HH * WW * FF / 4) / 256, 256, 0, stream>>>(mprt, hv, inv,
                                                             (float4*)out);
}

// Round 8
// 44.430 us; speedup vs baseline: 1.7797x; 1.1267x over previous
//
#include <hip/hip_runtime.h>

// Problem constants (fixed by setup_inputs): lfi [B,A,H,W,C], f_maps [B,H,W,F]
#define BB 4
#define AA 9
#define HH 256
#define WW 256
#define CC 9
#define FF 64

// ---------------------------------------------------------------------------
// Kernel 1 (round-1 verbatim, proven): hv[b,w,f] = mean_h f_maps[b,h,w,f]
// Block per (b,w): 256 threads = 4 h-lanes x 64 f; 256B/wave contiguous loads.
// ---------------------------------------------------------------------------
__global__ __launch_bounds__(256) void k_hv(const float* __restrict__ fm,
                                            float* __restrict__ hv) {
    const int blk = blockIdx.x;       // b*WW + w
    const int b = blk >> 8;           // WW == 256
    const int w = blk & 255;
    const int f = threadIdx.x & 63;
    const int hl = threadIdx.x >> 6;  // 0..3

    const float* base = fm + (((size_t)b * HH) * WW + w) * FF + f;
    float s = 0.f;
#pragma unroll 8
    for (int h = hl; h < HH; h += 4) {
        s += base[(size_t)h * WW * FF];
    }
    __shared__ float sm[256];
    sm[threadIdx.x] = s;
    __syncthreads();
    if (hl == 0) {
        float t = sm[f] + sm[64 + f] + sm[128 + f] + sm[192 + f];
        hv[(size_t)blk * FF + f] = t * (1.0f / HH);
    }
}

// ---------------------------------------------------------------------------
// Kernel 2 (round-1 verbatim, proven): inv[b,f] = 1 / max_w hv[b,w,f]
// Block per (b,f): 64 lanes x 4 w each + shuffle-max. L2-resident reads.
// ---------------------------------------------------------------------------
__global__ __launch_bounds__(64) void k_inv(const float* __restrict__ hv,
                                            float* __restrict__ inv) {
    const int b = blockIdx.x >> 6;
    const int f = blockIdx.x & 63;
    const int t = threadIdx.x;
    float mx = -1e30f;
#pragma unroll
    for (int j = 0; j < 4; ++j) {
        mx = fmaxf(mx, hv[((size_t)b * WW + (t + 64 * j)) * FF + f]);
    }
#pragma unroll
    for (int off = 32; off; off >>= 1)
        mx = fmaxf(mx, __shfl_xor(mx, off));
    if (t == 0) inv[blockIdx.x] = 1.0f / mx;
}

// ---------------------------------------------------------------------------
// Kernel 3: m[b,h,w] = mean_{a,c} lfi[b,a,h,w,c].
// Thread owns ONE hw cell; per a it loads the 3 overlapping float4s that
// cover its 9-float window (floats 9k..9k+8 always span exactly 3 float4s),
// then branchlessly sums window [r, r+9) of the 12 loaded floats, where
// r = t&3 (valid because 9 = 1 mod 4 and the block's base cell = 0 mod 4).
// vs round-1 scalar: 3 load instructions per a instead of 9 over the same
// 36-line span -> 3x fewer L1 transactions (the round-6-measured bottleneck).
// One accumulator, unroll 3 -> 9 loads in flight, low VGPR, no LDS/barriers.
// ---------------------------------------------------------------------------
__global__ __launch_bounds__(256) void k_m(const float* __restrict__ lfi,
                                           float* __restrict__ m) {
    const int t = threadIdx.x;
    const int k = blockIdx.x * 256 + t;   // global cell = b*65536 + h*256 + w
    const int b = k >> 16;                // HH*WW == 65536
    const int blk_local = blockIdx.x & 255;
    const int r = t & 3;                  // window start within 12 floats
    const size_t astride4 = (size_t)HH * WW * CC / 4;  // 147456 float4

    const float4* base = (const float4*)lfi + (size_t)b * AA * astride4 +
                         (size_t)blk_local * 576 + ((9 * t) >> 2);
    float acc = 0.f;
#pragma unroll 3
    for (int a = 0; a < AA; ++a) {
        const float4* p = base + (size_t)a * astride4;
        const float4 v0 = p[0], v1 = p[1], v2 = p[2];
        // w0..w11 = v0.xyzw v1.xyzw v2.xyzw; want sum of w[r..r+8]
        const float s12 = ((v0.x + v0.y) + (v0.z + v0.w)) +
                          ((v1.x + v1.y) + (v1.z + v1.w)) +
                          ((v2.x + v2.y) + (v2.z + v2.w));
        const float head = (r > 0 ? v0.x : 0.f) + (r > 1 ? v0.y : 0.f) +
                           (r > 2 ? v0.z : 0.f);
        const float tail = (r < 1 ? v2.y : 0.f) + (r < 2 ? v2.z : 0.f) +
                           (r < 3 ? v2.w : 0.f);
        acc += s12 - head - tail;
    }
    m[k] = acc * (1.0f / (AA * CC));
}

// ---------------------------------------------------------------------------
// Kernel 4 (round-1 verbatim, proven): out = m * hv[b,h,f] * inv[b,f]
// One thread per float4 along f; contiguous 16B/lane stores.
// ---------------------------------------------------------------------------
__global__ __launch_bounds__(256) void k_out(const float* __restrict__ m,
                                             const float* __restrict__ hv,
                                             const float* __restrict__ inv,
                                             float4* __restrict__ out) {
    const int idx = blockIdx.x * 256 + threadIdx.x;  // over B*H*W*F/4
    const int f4 = idx & 15;                         // FF/4 == 16
    const int rest = idx >> 4;                       // b*HH*WW + h*WW + w
    const int h = (rest >> 8) & 255;
    const int b = rest >> 16;

    const float mv = m[rest];
    const float4 hv4 = ((const float4*)hv)[((size_t)(b * HH + h)) * (FF / 4) + f4];
    const float4 iv4 = ((const float4*)inv)[b * (FF / 4) + f4];

    float4 o;
    o.x = mv * hv4.x * iv4.x;
    o.y = mv * hv4.y * iv4.y;
    o.z = mv * hv4.z * iv4.z;
    o.w = mv * hv4.w * iv4.w;
    out[idx] = o;
}

extern "C" void kernel_launch(void* const* d_in, const int* in_sizes, int n_in,
                              void* d_out, int out_size, void* d_ws, size_t ws_size,
                              hipStream_t stream) {
    const float* lfi = (const float*)d_in[0];  // [B,A,H,W,C] f32
    const float* fm  = (const float*)d_in[1];  // [B,H,W,F]   f32
    float* out = (float*)d_out;                // [B,H,W,F]   f32

    // Workspace layout (as round 1): hv 256KB | inv 1KB | m 1MB
    char* ws = (char*)d_ws;
    float* hv  = (float*)ws;
    float* inv = (float*)(ws + (size_t)BB * WW * FF * 4);
    float* m   = (float*)(ws + (size_t)BB * WW * FF * 4 + 1024);

    // 1) column means of f_maps
    k_hv<<<BB * WW, 256, 0, stream>>>(fm, hv);
    // 2) per-(b,f) reciprocal of max over w
    k_inv<<<BB * FF, 64, 0, stream>>>(hv, inv);
    // 3) angular mean of lfi (3-float4-window loads)
    k_m<<<(BB * HH * WW) / 256, 256, 0, stream>>>(lfi, m);
    // 4) broadcast-multiply into out
    k_out<<<(BB * HH * WW * FF / 4) / 256, 256, 0, stream>>>(m, hv, inv,
                                                             (float4*)out);
}

// Round 9
// 42.964 us; speedup vs baseline: 1.8404x; 1.0341x over previous
//
#include <hip/hip_runtime.h>

// Problem constants (fixed by setup_inputs): lfi [B,A,H,W,C], f_maps [B,H,W,F]
#define BB 4
#define AA 9
#define HH 256
#define WW 256
#define CC 9
#define FF 64

// ---------------------------------------------------------------------------
// Kernel 1 (round-1 verbatim, proven): hv[b,w,f] = mean_h f_maps[b,h,w,f]
// Block per (b,w): 256 threads = 4 h-lanes x 64 f; 256B/wave contiguous loads.
// ---------------------------------------------------------------------------
__global__ __launch_bounds__(256) void k_hv(const float* __restrict__ fm,
                                            float* __restrict__ hv) {
    const int blk = blockIdx.x;       // b*WW + w
    const int b = blk >> 8;           // WW == 256
    const int w = blk & 255;
    const int f = threadIdx.x & 63;
    const int hl = threadIdx.x >> 6;  // 0..3

    const float* base = fm + (((size_t)b * HH) * WW + w) * FF + f;
    float s = 0.f;
#pragma unroll 8
    for (int h = hl; h < HH; h += 4) {
        s += base[(size_t)h * WW * FF];
    }
    __shared__ float sm[256];
    sm[threadIdx.x] = s;
    __syncthreads();
    if (hl == 0) {
        float t = sm[f] + sm[64 + f] + sm[128 + f] + sm[192 + f];
        hv[(size_t)blk * FF + f] = t * (1.0f / HH);
    }
}

// ---------------------------------------------------------------------------
// Kernel 2: m[b,h,w] = mean_{a,c} lfi[b,a,h,w,c], with the round-1 k_inv
// dispatch folded in as rider blocks (saves one serial dispatch slot).
//  blocks [0,1024): m role (round-8 body: 3 overlapping float4s cover each
//    thread's 9-float window; branchless head/tail trim; 9 loads in flight).
//  blocks [1024,1088): inv role. Each of the 4 waves is one round-1 k_inv
//    block: pair=(b,f), 64 lanes x 4 w strided reads (L2-resident hv from
//    the previous dispatch) + shuffle-max -> inv[b,f] = 1/max. ~2us of work
//    across 256 waves, hidden under the m-role's HBM streaming.
// ---------------------------------------------------------------------------
__global__ __launch_bounds__(256) void k_m(const float* __restrict__ lfi,
                                           const float* __restrict__ hv,
                                           float* __restrict__ m,
                                           float* __restrict__ inv) {
    const int t = threadIdx.x;
    if (blockIdx.x < 1024) {
        const int k = blockIdx.x * 256 + t;  // b*65536 + h*256 + w
        const int b = k >> 16;               // HH*WW == 65536
        const int blk_local = blockIdx.x & 255;
        const int r = t & 3;                 // window start within 12 floats
        const size_t astride4 = (size_t)HH * WW * CC / 4;  // 147456 float4

        const float4* base = (const float4*)lfi + (size_t)b * AA * astride4 +
                             (size_t)blk_local * 576 + ((9 * t) >> 2);
        float acc = 0.f;
#pragma unroll 3
        for (int a = 0; a < AA; ++a) {
            const float4* p = base + (size_t)a * astride4;
            const float4 v0 = p[0], v1 = p[1], v2 = p[2];
            // w0..w11 = v0.xyzw v1.xyzw v2.xyzw; want sum of w[r..r+8]
            const float s12 = ((v0.x + v0.y) + (v0.z + v0.w)) +
                              ((v1.x + v1.y) + (v1.z + v1.w)) +
                              ((v2.x + v2.y) + (v2.z + v2.w));
            const float head = (r > 0 ? v0.x : 0.f) + (r > 1 ? v0.y : 0.f) +
                               (r > 2 ? v0.z : 0.f);
            const float tail = (r < 1 ? v2.y : 0.f) + (r < 2 ? v2.z : 0.f) +
                               (r < 3 ? v2.w : 0.f);
            acc += s12 - head - tail;
        }
        m[k] = acc * (1.0f / (AA * CC));
    } else {
        // inv role: wave = one (b,f) pair, round-1 k_inv body verbatim
        const int rb = blockIdx.x - 1024;    // 0..63
        const int wave = t >> 6;             // 0..3
        const int lane = t & 63;
        const int pair = rb * 4 + wave;      // 0..255
        const int b = pair >> 6;
        const int f = pair & 63;
        float mx = -1e30f;
#pragma unroll
        for (int j = 0; j < 4; ++j) {
            mx = fmaxf(mx, hv[((size_t)b * WW + (lane + 64 * j)) * FF + f]);
        }
#pragma unroll
        for (int off = 32; off; off >>= 1)
            mx = fmaxf(mx, __shfl_xor(mx, off));
        if (lane == 0) inv[pair] = 1.0f / mx;
    }
}

// ---------------------------------------------------------------------------
// Kernel 3 (round-1 verbatim, proven): out = m * hv[b,h,f] * inv[b,f]
// One thread per float4 along f; contiguous 16B/lane stores.
// ---------------------------------------------------------------------------
__global__ __launch_bounds__(256) void k_out(const float* __restrict__ m,
                                             const float* __restrict__ hv,
                                             const float* __restrict__ inv,
                                             float4* __restrict__ out) {
    const int idx = blockIdx.x * 256 + threadIdx.x;  // over B*H*W*F/4
    const int f4 = idx & 15;                         // FF/4 == 16
    const int rest = idx >> 4;                       // b*HH*WW + h*WW + w
    const int h = (rest >> 8) & 255;
    const int b = rest >> 16;

    const float mv = m[rest];
    const float4 hv4 = ((const float4*)hv)[((size_t)(b * HH + h)) * (FF / 4) + f4];
    const float4 iv4 = ((const float4*)inv)[b * (FF / 4) + f4];

    float4 o;
    o.x = mv * hv4.x * iv4.x;
    o.y = mv * hv4.y * iv4.y;
    o.z = mv * hv4.z * iv4.z;
    o.w = mv * hv4.w * iv4.w;
    out[idx] = o;
}

extern "C" void kernel_launch(void* const* d_in, const int* in_sizes, int n_in,
                              void* d_out, int out_size, void* d_ws, size_t ws_size,
                              hipStream_t stream) {
    const float* lfi = (const float*)d_in[0];  // [B,A,H,W,C] f32
    const float* fm  = (const float*)d_in[1];  // [B,H,W,F]   f32
    float* out = (float*)d_out;                // [B,H,W,F]   f32

    // Workspace layout (as round 1): hv 256KB | inv 1KB | m 1MB
    char* ws = (char*)d_ws;
    float* hv  = (float*)ws;
    float* inv = (float*)(ws + (size_t)BB * WW * FF * 4);
    float* m   = (float*)(ws + (size_t)BB * WW * FF * 4 + 1024);

    // 1) column means of f_maps
    k_hv<<<BB * WW, 256, 0, stream>>>(fm, hv);
    // 2) angular mean of lfi + inv rider blocks (replaces the k_inv dispatch)
    k_m<<<1024 + 64, 256, 0, stream>>>(lfi, hv, m, inv);
    // 3) broadcast-multiply into out
    k_out<<<(BB * HH * WW * FF / 4) / 256, 256, 0, stream>>>(m, hv, inv,
                                                             (float4*)out);
}